// Round 1
// baseline (608.072 us; speedup 1.0000x reference)
//
#include <hip/hip_runtime.h>
#include <hip/hip_bf16.h>

// Problem constants (from reference): B=65536 rows, F=256 features,
// T=256 trees, DEPTH=6, C=4 classes.
#define NB 65536
#define NF 256
#define NT 256
#define NC 4

// One block per row; thread t traverses tree t.
// LDS: x-row (256 f32) + leaf values staged with stride-5 padding
// (5 is coprime with 32 banks -> at most free 2-way aliasing on the
// class-column reads in the argmax phase).
__global__ __launch_bounds__(256) void tree_traverse_kernel(
    const float* __restrict__ x,           // [B, F]
    const int*   __restrict__ root_nodes,  // [T]
    const float* __restrict__ root_biases, // [T]
    const float* __restrict__ leaf_nodes,  // [T*64, C]
    const int*   __restrict__ n1, const float* __restrict__ b1,  // [T*2]
    const int*   __restrict__ n2, const float* __restrict__ b2,  // [T*4]
    const int*   __restrict__ n3, const float* __restrict__ b3,  // [T*8]
    const int*   __restrict__ n4, const float* __restrict__ b4,  // [T*16]
    const int*   __restrict__ n5, const float* __restrict__ b5,  // [T*32]
    float* __restrict__ out_arg,           // [B, C]   argmax over trees, as f32
    float* __restrict__ out_val)           // [B, T, C]
{
    const int b = blockIdx.x;
    const int t = threadIdx.x;

    __shared__ float xr[NF];
    __shared__ float vals[NT * 5];  // [tree][class] with leading-dim 5 padding

    // Stage this row's features: 256 threads x 1 coalesced load.
    xr[t] = x[(size_t)b * NF + t];
    __syncthreads();

    // Root split: prev = tree*2 + (x[feat] >= bias)
    int prev = t * 2 + (xr[root_nodes[t]] >= root_biases[t] ? 1 : 0);
    // Levels 1..5: prev = 2*prev + (x[nodes[prev]] >= biases[prev])
    prev = 2 * prev + (xr[n1[prev]] >= b1[prev] ? 1 : 0);
    prev = 2 * prev + (xr[n2[prev]] >= b2[prev] ? 1 : 0);
    prev = 2 * prev + (xr[n3[prev]] >= b3[prev] ? 1 : 0);
    prev = 2 * prev + (xr[n4[prev]] >= b4[prev] ? 1 : 0);
    prev = 2 * prev + (xr[n5[prev]] >= b5[prev] ? 1 : 0);
    // prev in [t*64, t*64+64): this tree's leaf row.

    const float4 leaf = *(const float4*)(leaf_nodes + (size_t)prev * NC);

    // Coalesced 16B/thread store of out[b, t, :].
    *(float4*)(out_val + ((size_t)b * NT + t) * NC) = leaf;

    vals[t * 5 + 0] = leaf.x;
    vals[t * 5 + 1] = leaf.y;
    vals[t * 5 + 2] = leaf.z;
    vals[t * 5 + 3] = leaf.w;
    __syncthreads();

    // Argmax over trees, per class. Wave w (4 waves) owns class w.
    // np.argmax tie-break: FIRST occurrence of the max wins.
    const int cls  = t >> 6;   // wave id = class
    const int lane = t & 63;

    float v   = vals[lane * 5 + cls];
    int   idx = lane;
    #pragma unroll
    for (int k = 1; k < 4; ++k) {
        const int tt = lane + 64 * k;           // strictly increasing index
        const float ov = vals[tt * 5 + cls];
        if (ov > v) { v = ov; idx = tt; }       // strict >: first occurrence wins
    }
    // Wave-64 reduction to lane 0; on equal values keep the lower tree index.
    #pragma unroll
    for (int off = 32; off > 0; off >>= 1) {
        const float ov = __shfl_down(v, off);
        const int   oi = __shfl_down(idx, off);
        if (ov > v || (ov == v && oi < idx)) { v = ov; idx = oi; }
    }
    if (lane == 0) out_arg[(size_t)b * NC + cls] = (float)idx;
}

extern "C" void kernel_launch(void* const* d_in, const int* in_sizes, int n_in,
                              void* d_out, int out_size, void* d_ws, size_t ws_size,
                              hipStream_t stream) {
    const float* x           = (const float*)d_in[0];
    const int*   root_nodes  = (const int*)  d_in[1];
    const float* root_biases = (const float*)d_in[2];
    const float* leaf_nodes  = (const float*)d_in[3];
    const int*   n1 = (const int*)  d_in[4];
    const float* b1 = (const float*)d_in[5];
    const int*   n2 = (const int*)  d_in[6];
    const float* b2 = (const float*)d_in[7];
    const int*   n3 = (const int*)  d_in[8];
    const float* b3 = (const float*)d_in[9];
    const int*   n4 = (const int*)  d_in[10];
    const float* b4 = (const float*)d_in[11];
    const int*   n5 = (const int*)  d_in[12];
    const float* b5 = (const float*)d_in[13];

    float* out_arg = (float*)d_out;                       // [B, C]
    float* out_val = (float*)d_out + (size_t)NB * NC;     // [B, T, C]

    tree_traverse_kernel<<<NB, 256, 0, stream>>>(
        x, root_nodes, root_biases, leaf_nodes,
        n1, b1, n2, b2, n3, b3, n4, b4, n5, b5,
        out_arg, out_val);
}

// Round 2
// 439.994 us; speedup vs baseline: 1.3820x; 1.3820x over previous
//
#include <hip/hip_runtime.h>
#include <hip/hip_bf16.h>

// B=65536 rows, F=256 features, T=256 trees, DEPTH=6, C=4 classes.
#define NB 65536
#define NF 256
#define NT 256
#define NC 4
#define NG 8            // tree groups (32 trees each)
#define TG 32           // trees per group
#define RPB 512         // rows per block
#define RPC 8           // rows per chunk
#define NCHUNK (RPB / RPC)   // 64
#define NTHREADS 256

// Order-preserving float32 -> uint32 map (total order, no NaNs in input).
__device__ __forceinline__ unsigned int mono32(float v) {
    unsigned int u = __float_as_uint(v);
    return (u & 0x80000000u) ? ~u : (u | 0x80000000u);
}

// Block = (tree-group g of 32 trees) x (row-block rb of 512 rows).
// Node/bias tables for the group packed as int2 in LDS (one ds_read_b64 per
// level instead of two 64-way-divergent global loads). x-rows staged in LDS,
// 8 rows per chunk. Leaf read stays global (256 KB, L2-hot).
// Per-(row,class) argmax folded over the group's 32 trees in LDS, then merged
// across the 8 groups with a monotone u64 key + device-scope atomicMax in ws.
__global__ __launch_bounds__(NTHREADS) void k_traverse(
    const float* __restrict__ x,
    const int*   __restrict__ root_nodes, const float* __restrict__ root_biases,
    const float* __restrict__ leaf_nodes,
    const int* __restrict__ n1, const float* __restrict__ b1,
    const int* __restrict__ n2, const float* __restrict__ b2,
    const int* __restrict__ n3, const float* __restrict__ b3,
    const int* __restrict__ n4, const float* __restrict__ b4,
    const int* __restrict__ n5, const float* __restrict__ b5,
    float* __restrict__ out_val,                 // [B, T, C]
    unsigned long long* __restrict__ keys)       // [B, C] argmax keys
{
    const int g  = blockIdx.x >> 7;   // tree group 0..7
    const int rb = blockIdx.x & 127;  // row block 0..127

    __shared__ int2  rt[TG];           // root (node, bias-bits)
    __shared__ int2  tbl[1984];        // levels 1..5, bases 0/64/192/448/960
    __shared__ float xr[RPC * NF];     // 8 staged rows
    __shared__ float vals[RPC * 165];  // [rs]*165 + lt*5 + cls (bank-spread)

    const int tid = threadIdx.x;

    // ---- stage this group's tables (once per block), coalesced ----
    if (tid < TG)
        rt[tid] = make_int2(root_nodes[g * TG + tid],
                            __float_as_int(root_biases[g * TG + tid]));
    {
        const int*   ns[5] = { n1, n2, n3, n4, n5 };
        const float* bs[5] = { b1, b2, b3, b4, b5 };
        int base = 0;
        #pragma unroll
        for (int l = 1; l <= 5; ++l) {
            const int n  = TG << l;          // 64,128,256,512,1024
            const int gb = g * n;            // group slice offset in global table
            const int*   np = ns[l - 1];
            const float* bp = bs[l - 1];
            for (int i = tid; i < n; i += NTHREADS)
                tbl[base + i] = make_int2(np[gb + i], __float_as_int(bp[gb + i]));
            base += n;
        }
    }

    const float4* xg  = (const float4*)x;
    const float4* lf4 = (const float4*)leaf_nodes;
    float4*       ov4 = (float4*)out_val;

    const int rs = tid >> 5;   // row within chunk 0..7
    const int lt = tid & 31;   // local tree 0..31
    const int t  = g * TG + lt;

    for (int c = 0; c < NCHUNK; ++c) {
        const int r0 = rb * RPB + c * RPC;

        // stage 8 rows = 512 float4, coalesced
        {
            const size_t base4 = (size_t)r0 * (NF / 4);
            float4* xr4 = (float4*)xr;
            xr4[tid]       = xg[base4 + tid];
            xr4[tid + 256] = xg[base4 + tid + 256];
        }
        __syncthreads();   // tables ready (first iter) + xr ready

        // ---- traversal: all gathers from LDS ----
        const float* xrow = xr + rs * NF;
        int2 e = rt[lt];
        int p = (lt << 1) + (xrow[e.x] >= __int_as_float(e.y) ? 1 : 0);
        e = tbl[p];        p = (p << 1) + (xrow[e.x] >= __int_as_float(e.y) ? 1 : 0);
        e = tbl[64 + p];   p = (p << 1) + (xrow[e.x] >= __int_as_float(e.y) ? 1 : 0);
        e = tbl[192 + p];  p = (p << 1) + (xrow[e.x] >= __int_as_float(e.y) ? 1 : 0);
        e = tbl[448 + p];  p = (p << 1) + (xrow[e.x] >= __int_as_float(e.y) ? 1 : 0);
        e = tbl[960 + p];  p = (p << 1) + (xrow[e.x] >= __int_as_float(e.y) ? 1 : 0);
        // p in [0, 2048): local leaf row

        const float4 leaf = lf4[(size_t)g * 2048 + p];
        const int row = r0 + rs;
        ov4[(size_t)row * NT + t] = leaf;   // coalesced (2 runs of 512 B / wave)

        float* vp = vals + rs * 165 + lt * 5;
        vp[0] = leaf.x; vp[1] = leaf.y; vp[2] = leaf.z; vp[3] = leaf.w;
        __syncthreads();   // vals ready; also protects xr/vals reuse next iter

        // ---- per-(row,class) argmax over this group's 32 trees ----
        if (tid < 32) {
            const int frs  = tid >> 2;    // row 0..7
            const int fcls = tid & 3;     // class 0..3
            const float* vb = vals + frs * 165 + fcls;
            float v = vb[0];
            int  bi = 0;
            #pragma unroll
            for (int j = 1; j < 32; ++j) {       // ascending tree, strict >
                const float w = vb[j * 5];
                if (w > v) { v = w; bi = j; }    // first occurrence wins
            }
            const unsigned long long key =
                ((unsigned long long)mono32(v) << 8) |
                (unsigned long long)(255 - (g * TG + bi));  // ties -> lower tree
            atomicMax(&keys[(size_t)(r0 + frs) * NC + fcls], key);
        }
    }
}

__global__ __launch_bounds__(256) void k_finish(
    const unsigned long long* __restrict__ keys,
    float* __restrict__ out_arg)   // [B, C]
{
    const int i = blockIdx.x * 256 + threadIdx.x;
    out_arg[i] = (float)(255 - (int)(keys[i] & 0xFFull));
}

extern "C" void kernel_launch(void* const* d_in, const int* in_sizes, int n_in,
                              void* d_out, int out_size, void* d_ws, size_t ws_size,
                              hipStream_t stream) {
    const float* x           = (const float*)d_in[0];
    const int*   root_nodes  = (const int*)  d_in[1];
    const float* root_biases = (const float*)d_in[2];
    const float* leaf_nodes  = (const float*)d_in[3];
    const int*   n1 = (const int*)  d_in[4];
    const float* b1 = (const float*)d_in[5];
    const int*   n2 = (const int*)  d_in[6];
    const float* b2 = (const float*)d_in[7];
    const int*   n3 = (const int*)  d_in[8];
    const float* b3 = (const float*)d_in[9];
    const int*   n4 = (const int*)  d_in[10];
    const float* b4 = (const float*)d_in[11];
    const int*   n5 = (const int*)  d_in[12];
    const float* b5 = (const float*)d_in[13];

    float* out_arg = (float*)d_out;                    // [B, C]
    float* out_val = (float*)d_out + (size_t)NB * NC;  // [B, T, C]
    unsigned long long* keys = (unsigned long long*)d_ws;  // [B*C] u64

    hipMemsetAsync(d_ws, 0, (size_t)NB * NC * sizeof(unsigned long long), stream);

    k_traverse<<<NG * 128, NTHREADS, 0, stream>>>(
        x, root_nodes, root_biases, leaf_nodes,
        n1, b1, n2, b2, n3, b3, n4, b4, n5, b5,
        out_val, keys);

    k_finish<<<(NB * NC) / 256, 256, 0, stream>>>(keys, out_arg);
}

// Round 3
// 416.860 us; speedup vs baseline: 1.4587x; 1.0555x over previous
//
#include <hip/hip_runtime.h>
#include <hip/hip_bf16.h>

// B=65536 rows, F=256 features, T=256 trees, DEPTH=6, C=4 classes.
#define NB 65536
#define NF 256
#define NT 256
#define NC 4
#define NG 8             // tree groups (32 trees each)
#define TG 32
#define RB 128           // row-blocks
#define RPB (NB / RB)    // 512 rows per block
#define RPC 16           // rows per chunk (2 chains per thread)
#define NCHUNK (RPB / RPC)  // 32
#define NTHREADS 256

// Order-preserving float32 -> uint32 (inputs have no NaNs).
__device__ __forceinline__ unsigned int mono32(float v) {
    unsigned int u = __float_as_uint(v);
    return (u & 0x80000000u) ? ~u : (u | 0x80000000u);
}

// Block = (tree-group g, 32 trees) x (row-block rb, 512 rows).
// Levels 0..2 of each thread's tree live in REGISTERS (reachable entries:
// 1+2+4 int2); levels 3..5 in LDS (14.3 KB). Each thread walks TWO rows
// (independent dependent-LDS chains -> 2x latency hiding). Argmax over the
// group's 32 trees: shfl_xor max-butterfly + ballot/ffs (first occurrence),
// merged across groups via monotone-u64 atomicMax in ws.
__global__ __launch_bounds__(NTHREADS, 4) void k_traverse(
    const float* __restrict__ x,
    const int*   __restrict__ root_nodes, const float* __restrict__ root_biases,
    const float* __restrict__ leaf_nodes,
    const int* __restrict__ n1, const float* __restrict__ b1,
    const int* __restrict__ n2, const float* __restrict__ b2,
    const int* __restrict__ n3, const float* __restrict__ b3,
    const int* __restrict__ n4, const float* __restrict__ b4,
    const int* __restrict__ n5, const float* __restrict__ b5,
    float* __restrict__ out_val,                 // [B, T, C]
    unsigned long long* __restrict__ keys)       // [B, C]
{
    const int g  = blockIdx.x >> 7;        // tree group 0..7
    const int rb = blockIdx.x & (RB - 1);  // row block 0..127

    __shared__ int2  tbl[1792];     // l3 @0 (256), l4 @256 (512), l5 @768 (1024)
    __shared__ float xr[RPC * NF];  // 16 staged rows (16 KB)

    const int tid = threadIdx.x;
    const int rs  = tid >> 5;       // row slot 0..7
    const int lt  = tid & 31;       // local tree
    const int t   = g * TG + lt;    // global tree

    // ---- per-thread register tables: root + levels 1,2 ----
    const int2 e0   = make_int2(root_nodes[t], __float_as_int(root_biases[t]));
    const int2 e1_0 = make_int2(n1[2 * t],     __float_as_int(b1[2 * t]));
    const int2 e1_1 = make_int2(n1[2 * t + 1], __float_as_int(b1[2 * t + 1]));
    const int2 e2_0 = make_int2(n2[4 * t],     __float_as_int(b2[4 * t]));
    const int2 e2_1 = make_int2(n2[4 * t + 1], __float_as_int(b2[4 * t + 1]));
    const int2 e2_2 = make_int2(n2[4 * t + 2], __float_as_int(b2[4 * t + 2]));
    const int2 e2_3 = make_int2(n2[4 * t + 3], __float_as_int(b2[4 * t + 3]));

    // ---- stage levels 3..5 for this group into LDS (coalesced) ----
    tbl[tid] = make_int2(n3[g * 256 + tid], __float_as_int(b3[g * 256 + tid]));
    #pragma unroll
    for (int k = 0; k < 2; ++k) {
        const int i = tid + 256 * k;
        tbl[256 + i] = make_int2(n4[g * 512 + i], __float_as_int(b4[g * 512 + i]));
    }
    #pragma unroll
    for (int k = 0; k < 4; ++k) {
        const int i = tid + 256 * k;
        tbl[768 + i] = make_int2(n5[g * 1024 + i], __float_as_int(b5[g * 1024 + i]));
    }

    const float4* xg  = (const float4*)x;
    const float4* lf4 = (const float4*)leaf_nodes;
    float4*       ov4 = (float4*)out_val;
    const int halfshift = tid & 32;   // ballot half select

    for (int ck = 0; ck < NCHUNK; ++ck) {
        const int r0 = rb * RPB + ck * RPC;

        // stage 16 rows = 1024 float4, coalesced
        {
            const size_t base4 = (size_t)r0 * (NF / 4);
            float4* xr4 = (float4*)xr;
            #pragma unroll
            for (int k = 0; k < 4; ++k)
                xr4[tid + 256 * k] = xg[base4 + tid + 256 * k];
        }
        __syncthreads();

        const float* xrow0 = xr + rs * NF;
        const float* xrow1 = xr + (rs + 8) * NF;
        int p0, p1;
        int2 ea, eb;

        // root (regs)
        p0 = (xrow0[e0.x] >= __int_as_float(e0.y)) ? 1 : 0;
        p1 = (xrow1[e0.x] >= __int_as_float(e0.y)) ? 1 : 0;
        // level 1 (regs)
        ea = p0 ? e1_1 : e1_0;
        eb = p1 ? e1_1 : e1_0;
        p0 = 2 * p0 + (xrow0[ea.x] >= __int_as_float(ea.y) ? 1 : 0);
        p1 = 2 * p1 + (xrow1[eb.x] >= __int_as_float(eb.y) ? 1 : 0);
        // level 2 (regs, 4-way select)
        {
            int2 a0 = (p0 & 1) ? e2_1 : e2_0, a1 = (p0 & 1) ? e2_3 : e2_2;
            ea = (p0 & 2) ? a1 : a0;
            int2 c0 = (p1 & 1) ? e2_1 : e2_0, c1 = (p1 & 1) ? e2_3 : e2_2;
            eb = (p1 & 2) ? c1 : c0;
        }
        p0 = 2 * p0 + (xrow0[ea.x] >= __int_as_float(ea.y) ? 1 : 0);
        p1 = 2 * p1 + (xrow1[eb.x] >= __int_as_float(eb.y) ? 1 : 0);
        // level 3 (LDS)
        ea = tbl[(lt << 3) + p0];
        eb = tbl[(lt << 3) + p1];
        p0 = 2 * p0 + (xrow0[ea.x] >= __int_as_float(ea.y) ? 1 : 0);
        p1 = 2 * p1 + (xrow1[eb.x] >= __int_as_float(eb.y) ? 1 : 0);
        // level 4 (LDS)
        ea = tbl[256 + (lt << 4) + p0];
        eb = tbl[256 + (lt << 4) + p1];
        p0 = 2 * p0 + (xrow0[ea.x] >= __int_as_float(ea.y) ? 1 : 0);
        p1 = 2 * p1 + (xrow1[eb.x] >= __int_as_float(eb.y) ? 1 : 0);
        // level 5 (LDS)
        ea = tbl[768 + (lt << 5) + p0];
        eb = tbl[768 + (lt << 5) + p1];
        p0 = 2 * p0 + (xrow0[ea.x] >= __int_as_float(ea.y) ? 1 : 0);
        p1 = 2 * p1 + (xrow1[eb.x] >= __int_as_float(eb.y) ? 1 : 0);

        // leaves (global, L2-hot) + coalesced out_val stores
        const float4 leaf0 = lf4[(size_t)g * 2048 + (lt << 6) + p0];
        const float4 leaf1 = lf4[(size_t)g * 2048 + (lt << 6) + p1];
        ov4[(size_t)(r0 + rs)     * NT + t] = leaf0;
        ov4[(size_t)(r0 + rs + 8) * NT + t] = leaf1;

        // ---- argmax over this group's 32 trees, per (row,class) ----
        #pragma unroll
        for (int c = 0; c < 2; ++c) {
            const float4 lv = c ? leaf1 : leaf0;
            const int row = r0 + rs + 8 * c;
            unsigned long long kk[4];
            const float vc[4] = { lv.x, lv.y, lv.z, lv.w };
            #pragma unroll
            for (int cls = 0; cls < 4; ++cls) {
                float m = vc[cls];
                #pragma unroll
                for (int msk = 16; msk >= 1; msk >>= 1)
                    m = fmaxf(m, __shfl_xor(m, msk));
                const unsigned long long ball = __ballot(vc[cls] == m);
                const unsigned int hm = (unsigned int)(ball >> halfshift);
                const int gidx = g * TG + (__ffs(hm) - 1);   // first occurrence
                kk[cls] = ((unsigned long long)mono32(m) << 8) |
                          (unsigned long long)(255 - gidx);
            }
            if (lt < 4) {
                unsigned long long k = (lt == 0) ? kk[0] :
                                       (lt == 1) ? kk[1] :
                                       (lt == 2) ? kk[2] : kk[3];
                atomicMax(&keys[(size_t)row * NC + lt], k);
            }
        }
        __syncthreads();   // protect xr before next chunk's staging
    }
}

__global__ __launch_bounds__(256) void k_finish(
    const unsigned long long* __restrict__ keys,
    float* __restrict__ out_arg)   // [B, C]
{
    const int i = blockIdx.x * 256 + threadIdx.x;
    out_arg[i] = (float)(255 - (int)(keys[i] & 0xFFull));
}

extern "C" void kernel_launch(void* const* d_in, const int* in_sizes, int n_in,
                              void* d_out, int out_size, void* d_ws, size_t ws_size,
                              hipStream_t stream) {
    const float* x           = (const float*)d_in[0];
    const int*   root_nodes  = (const int*)  d_in[1];
    const float* root_biases = (const float*)d_in[2];
    const float* leaf_nodes  = (const float*)d_in[3];
    const int*   n1 = (const int*)  d_in[4];
    const float* b1 = (const float*)d_in[5];
    const int*   n2 = (const int*)  d_in[6];
    const float* b2 = (const float*)d_in[7];
    const int*   n3 = (const int*)  d_in[8];
    const float* b3 = (const float*)d_in[9];
    const int*   n4 = (const int*)  d_in[10];
    const float* b4 = (const float*)d_in[11];
    const int*   n5 = (const int*)  d_in[12];
    const float* b5 = (const float*)d_in[13];

    float* out_arg = (float*)d_out;                    // [B, C]
    float* out_val = (float*)d_out + (size_t)NB * NC;  // [B, T, C]
    unsigned long long* keys = (unsigned long long*)d_ws;

    hipMemsetAsync(d_ws, 0, (size_t)NB * NC * sizeof(unsigned long long), stream);

    k_traverse<<<NG * RB, NTHREADS, 0, stream>>>(
        x, root_nodes, root_biases, leaf_nodes,
        n1, b1, n2, b2, n3, b3, n4, b4, n5, b5,
        out_val, keys);

    k_finish<<<(NB * NC) / 256, 256, 0, stream>>>(keys, out_arg);
}